// Round 17
// baseline (3014.796 us; speedup 1.0000x reference)
//
#include <hip/hip_runtime.h>
#include <hip/hip_bf16.h>

#define BB 2
#define TT 1023
#define CC 1024
#define HH 16
#define HSZ 64
#define LL 6
#define FFD 4096
#define VV 50258
#define MM (BB*TT)   // 2046
#define MP 2048      // padded row count
#define VP 50304     // padded vocab (multiple of 128)

typedef __attribute__((ext_vector_type(4))) float  f32x4;
typedef __attribute__((ext_vector_type(8))) short  s16x8;
typedef __attribute__((ext_vector_type(4))) short  s16x4;

#define SCHED0   __builtin_amdgcn_sched_barrier(0)
#define SBAR     __builtin_amdgcn_s_barrier()
#define LGKMCNT0 asm volatile("s_waitcnt lgkmcnt(0)" ::: "memory")

__device__ __forceinline__ short f2b(float x) {
    __hip_bfloat16 h = __float2bfloat16(x);
    short s;
    __builtin_memcpy(&s, &h, 2);
    return s;
}
__device__ __forceinline__ float b2f(short s) {
    unsigned u = ((unsigned)(unsigned short)s) << 16;
    float f;
    __builtin_memcpy(&f, &u, 4);
    return f;
}

__device__ __forceinline__ void gld16(const void* g, void* l) {
    __builtin_amdgcn_global_load_lds(
        (__attribute__((address_space(1))) const void*)g,
        (__attribute__((address_space(3))) void*)l, 16, 0, 0);
}

// ---------------------------------------------------------------------------
// Embedding: fp32 + bf16 mirror
// ---------------------------------------------------------------------------
__global__ __launch_bounds__(256) void embed_kernel(
    const int* __restrict__ ids, const float* __restrict__ wte,
    const float* __restrict__ wpe, float* __restrict__ out,
    __hip_bfloat16* __restrict__ outb)
{
    int r = blockIdx.x;
    int t = r % TT;
    long id = ids[r];
    int c = threadIdx.x * 4;
    float4 a = *(const float4*)(wte + id * (long)CC + c);
    float4 p = *(const float4*)(wpe + (long)t * CC + c);
    float4 o; o.x = a.x + p.x; o.y = a.y + p.y; o.z = a.z + p.z; o.w = a.w + p.w;
    *(float4*)(out + (long)r * CC + c) = o;
    s16x4 h; h[0] = f2b(o.x); h[1] = f2b(o.y); h[2] = f2b(o.z); h[3] = f2b(o.w);
    *(s16x4*)(outb + (long)r * CC + c) = h;
}

// ---------------------------------------------------------------------------
// Elementwise fp32 -> bf16
// ---------------------------------------------------------------------------
__global__ __launch_bounds__(256) void cvtb_kernel(
    const float* __restrict__ in, __hip_bfloat16* __restrict__ out, long n)
{
    long i = ((long)blockIdx.x * 256 + threadIdx.x) * 8;
    if (i >= n) return;
    float4 f0 = *(const float4*)(in + i);
    float4 f1 = *(const float4*)(in + i + 4);
    s16x8 h;
    h[0]=f2b(f0.x); h[1]=f2b(f0.y); h[2]=f2b(f0.z); h[3]=f2b(f0.w);
    h[4]=f2b(f1.x); h[5]=f2b(f1.y); h[6]=f2b(f1.z); h[7]=f2b(f1.w);
    *(s16x8*)(out + i) = h;
}

// ---------------------------------------------------------------------------
// Transpose + fp32->bf16: in [R][S] fp32 -> out [S][R] bf16, batched over z.
// ---------------------------------------------------------------------------
__global__ __launch_bounds__(256) void tcvt_kernel(
    const float* __restrict__ in, __hip_bfloat16* __restrict__ out,
    int R, int S, long inZ, long outZa, long outZb, int zdiv)
{
    int z = blockIdx.z;
    in  += (long)z * inZ;
    out += (long)(z / zdiv) * outZa + (long)(z % zdiv) * outZb;
    __shared__ float tile[32][33];
    int s0 = blockIdx.x * 32, r0 = blockIdx.y * 32;
    int tx = threadIdx.x, ty = threadIdx.y;
    #pragma unroll
    for (int i = 0; i < 4; ++i)
        tile[ty + i * 8][tx] = in[(long)(r0 + ty + i * 8) * S + s0 + tx];
    __syncthreads();
    #pragma unroll
    for (int i = 0; i < 4; ++i)
        out[(long)(s0 + ty + i * 8) * R + r0 + tx] =
            __float2bfloat16(tile[tx][ty + i * 8]);
}

// ---------------------------------------------------------------------------
// bf16 MFMA GEMM, T3+T4 pipelined, T2-swizzled, XCD-swizzled.
// Tile (BM,BN) in {(128,128),(64,128)} - r12 local optimum.
// SPLITK: single launch, doubled grid; block half ks reduces K over
// [ks*K, ks*K+K) of Kstride-long rows; ks=0 -> Cb/ldc (with bias),
// ks=1 -> Cb2/ldc2.  Consumer sums the two bf16 partials in fp32.
// 3 LDS buffers, 2-deep prefetch, counted vmcnt (2L/L/0), raw s_barrier,
// setprio around MFMA.
// WMODE: 0 = fp32 out (float2-coalesced), 2 = bf16 out (b128-coalesced).
// ---------------------------------------------------------------------------
template<int WMODE, bool RELU, int BM, int BN, bool SPLITK>
__global__ __launch_bounds__(256) void mgemm2_kernel(
    const __hip_bfloat16* __restrict__ A, const __hip_bfloat16* __restrict__ B,
    const float* __restrict__ bias, float* __restrict__ Cm,
    __hip_bfloat16* __restrict__ Cb, __hip_bfloat16* __restrict__ Cb2,
    int M, int N, int K, int Kstride, int ldc, int ldc2, int GM)
{
    constexpr int ASZ  = BM * 32;
    constexpr int BSZ  = BN * 32;
    constexpr int BUF  = ASZ + BSZ;
    constexpr int WROW = BM / 2;
    constexpr int WCOL = BN / 2;
    constexpr int NI   = WROW / 16;
    constexpr int NJ   = WCOL / 16;
    constexpr int NAC  = BM / 64;          // A chunks per wave
    constexpr int NBC  = BN / 64;          // B chunks per wave
    constexpr int L    = NAC + NBC;        // gld16 per thread per stage
    __shared__ short LDS[3 * BUF];

    // bijective XCD swizzle + m-fastest decode
    const int nwg = gridDim.x;
    const int bid = blockIdx.x;
    const int q = nwg >> 3, r = nwg & 7;
    const int xcd = bid & 7, lid = bid >> 3;
    int swz = (xcd < r) ? xcd * (q + 1) + lid
                        : r * (q + 1) + (xcd - r) * q + lid;
    int ks = 0;
    if (SPLITK) {
        const int hN = nwg >> 1;
        ks = (swz >= hN);
        swz -= ks * hN;
    }
    const int m0 = (swz % GM) * BM;
    const int n0 = (swz / GM) * BN;

    const int tid  = threadIdx.x;
    const int lane = tid & 63, w = tid >> 6;
    const int wr = w >> 1, wc = w & 1;
    const int lr = lane & 15, kg = lane >> 4;

    const __hip_bfloat16* Abase = A + (long)m0 * Kstride + (SPLITK ? ks * K : 0);
    const __hip_bfloat16* Bbase = B + (long)n0 * Kstride + (SPLITK ? ks * K : 0);
    const float* biasU = (SPLITK && ks) ? nullptr : bias;
    __hip_bfloat16* CbU = (SPLITK && ks) ? Cb2 : Cb;
    const int ldcU = (SPLITK && ks) ? ldc2 : ldc;

    f32x4 acc[NI][NJ];
    #pragma unroll
    for (int i = 0; i < NI; ++i)
        #pragma unroll
        for (int j = 0; j < NJ; ++j)
            acc[i][j] = (f32x4){0.f, 0.f, 0.f, 0.f};

    const int srow = lane >> 2;
    const int scol = (((lane & 3) ^ ((lane >> 3) & 3))) * 8;   // swizzled src

    auto stage = [&](int db, long kofs) {
        short* Ad = &LDS[db * BUF];
        short* Bd = Ad + ASZ;
        #pragma unroll
        for (int p = 0; p < NAC; ++p) {
            int cc = p * 4 + w;
            long ro = (long)(cc * 16 + srow) * Kstride + kofs + scol;
            gld16(Abase + ro, Ad + cc * 512);
        }
        #pragma unroll
        for (int p = 0; p < NBC; ++p) {
            int cc = p * 4 + w;
            long ro = (long)(cc * 16 + srow) * Kstride + kofs + scol;
            gld16(Bbase + ro, Bd + cc * 512);
        }
    };
    const int rslot = (kg ^ ((lr >> 1) & 3)) * 8;

    auto compute = [&](int db) {
        const short* Ar = &LDS[db * BUF];
        const short* Br = Ar + ASZ;
        s16x8 af[NI], bf[NJ];
        #pragma unroll
        for (int i = 0; i < NI; ++i)
            af[i] = *(const s16x8*)&Ar[(wr * WROW + i * 16 + lr) * 32 + rslot];
        #pragma unroll
        for (int j = 0; j < NJ; ++j)
            bf[j] = *(const s16x8*)&Br[(wc * WCOL + j * 16 + lr) * 32 + rslot];
        __builtin_amdgcn_s_setprio(1);
        #pragma unroll
        for (int i = 0; i < NI; ++i)
            #pragma unroll
            for (int j = 0; j < NJ; ++j)
                acc[i][j] = __builtin_amdgcn_mfma_f32_16x16x32_bf16(
                    af[i], bf[j], acc[i][j], 0, 0, 0);
        __builtin_amdgcn_s_setprio(0);
    };

    const int nt = K >> 5;
    stage(0, 0);
    if (nt > 1) stage(1, 32);
    int db = 0;
    for (int t = 0; t < nt; ++t) {
        if (t + 2 < nt) {
            stage((db + 2) % 3, (long)(t + 2) << 5);
            SCHED0;
            if constexpr (L == 4) asm volatile("s_waitcnt vmcnt(8)" ::: "memory");
            else asm volatile("s_waitcnt vmcnt(6)" ::: "memory");
            SCHED0;
        } else if (t + 1 < nt) {
            SCHED0;
            if constexpr (L == 4) asm volatile("s_waitcnt vmcnt(4)" ::: "memory");
            else asm volatile("s_waitcnt vmcnt(3)" ::: "memory");
            SCHED0;
        } else {
            SCHED0; asm volatile("s_waitcnt vmcnt(0)" ::: "memory"); SCHED0;
        }
        SBAR; SCHED0;
        compute(db);
        SCHED0; LGKMCNT0; SCHED0; SBAR; SCHED0;
        db = (db + 1) % 3;
    }

    // ---- epilogue: stage C tile through LDS for coalesced stores ----
    if (WMODE == 0) {
        float* LF = (float*)&LDS[0];
        if (BM == 128) {
            // [128][64] fp32 half-tiles
            #pragma unroll
            for (int h = 0; h < 2; ++h) {
                if (wc == h) {
                    #pragma unroll
                    for (int j = 0; j < NJ; ++j) {
                        int gcol = n0 + h * WCOL + j * 16 + lr;
                        float bv = (biasU && gcol < N) ? biasU[gcol] : 0.f;
                        #pragma unroll
                        for (int i = 0; i < NI; ++i) {
                            int row0 = wr * WROW + i * 16 + kg * 4;
                            #pragma unroll
                            for (int qq = 0; qq < 4; ++qq) {
                                float v = acc[i][j][qq] + bv;
                                if (RELU) v = fmaxf(v, 0.f);
                                LF[(row0 + qq) * 64 + j * 16 + lr] = v;
                            }
                        }
                    }
                }
                __syncthreads();
                #pragma unroll
                for (int i = 0; i < 16; ++i) {
                    int F = i * 256 + tid;
                    int row = F >> 5, col = (F & 31) * 2;
                    int gr = m0 + row, gc = n0 + h * 64 + col;
                    if (gr < M && gc < N)
                        *(float2*)(Cm + (long)gr * ldc + gc) = *(const float2*)&LF[row * 64 + col];
                }
                __syncthreads();
            }
        } else {
            // full [BM][BN] fp32 tile
            #pragma unroll
            for (int j = 0; j < NJ; ++j) {
                int gcol = n0 + wc * WCOL + j * 16 + lr;
                float bv = (biasU && gcol < N) ? biasU[gcol] : 0.f;
                #pragma unroll
                for (int i = 0; i < NI; ++i) {
                    int row0 = wr * WROW + i * 16 + kg * 4;
                    #pragma unroll
                    for (int qq = 0; qq < 4; ++qq) {
                        float v = acc[i][j][qq] + bv;
                        if (RELU) v = fmaxf(v, 0.f);
                        LF[(row0 + qq) * BN + wc * WCOL + j * 16 + lr] = v;
                    }
                }
            }
            __syncthreads();
            #pragma unroll
            for (int i = 0; i < BM * BN / 512; ++i) {
                int F = i * 256 + tid;
                int row = F / (BN / 2), col = (F % (BN / 2)) * 2;
                int gr = m0 + row, gc = n0 + col;
                if (gr < M && gc < N)
                    *(float2*)(Cm + (long)gr * ldc + gc) = *(const float2*)&LF[row * BN + col];
            }
        }
    } else {
        short* LS = (short*)&LDS[0];       // [BM][BN] bf16
        #pragma unroll
        for (int j = 0; j < NJ; ++j) {
            int gcol = n0 + wc * WCOL + j * 16 + lr;
            float bv = (biasU && gcol < N) ? biasU[gcol] : 0.f;
            #pragma unroll
            for (int i = 0; i < NI; ++i) {
                int row0 = wr * WROW + i * 16 + kg * 4;
                #pragma unroll
                for (int qq = 0; qq < 4; ++qq) {
                    float v = acc[i][j][qq] + bv;
                    if (RELU) v = fmaxf(v, 0.f);
                    LS[(row0 + qq) * BN + wc * WCOL + j * 16 + lr] = f2b(v);
                }
            }
        }
        __syncthreads();
        #pragma unroll
        for (int i = 0; i < BM * BN / 2048; ++i) {
            int F = i * 256 + tid;
            int row = F / (BN / 8), col = (F % (BN / 8)) * 8;
            int gr = m0 + row, gc = n0 + col;
            if (gr < M && gc < N)
                *(s16x8*)((short*)CbU + (long)gr * ldcU + gc) = *(const s16x8*)&LS[row * BN + col];
        }
    }
}

// ---------------------------------------------------------------------------
// Fallback fp32-B GEMM (logits only, if ws too small for bf16 wte mirror).
// ---------------------------------------------------------------------------
__global__ __launch_bounds__(256) void mgemm_f32b_kernel(
    const float* __restrict__ A, const float* __restrict__ Bv,
    const float* __restrict__ bias, float* __restrict__ Cm,
    int M, int N, int K, int ldc)
{
    __shared__ short As[128][40];
    __shared__ short Bs[128][40];
    const int tid  = threadIdx.x;
    const int lane = tid & 63, w = tid >> 6;
    const int wr = w >> 1, wc = w & 1;
    const int lr = lane & 15, kg = lane >> 4;
    const int m0 = blockIdx.y * 128, n0 = blockIdx.x * 128;
    const int ar = tid >> 3, ac = (tid & 7) * 4;
    const int br = tid >> 2, bc = (tid & 3) * 8;

    f32x4 acc[4][4];
    #pragma unroll
    for (int i = 0; i < 4; ++i)
        #pragma unroll
        for (int j = 0; j < 4; ++j)
            acc[i][j] = (f32x4){0.f, 0.f, 0.f, 0.f};

    for (int k0 = 0; k0 < K; k0 += 32) {
        #pragma unroll
        for (int p = 0; p < 4; ++p) {
            int row = ar + p * 32, gm = m0 + row;
            float4 f = {0.f, 0.f, 0.f, 0.f};
            if (gm < M) f = *(const float4*)(A + (long)gm * K + k0 + ac);
            s16x4 h; h[0] = f2b(f.x); h[1] = f2b(f.y); h[2] = f2b(f.z); h[3] = f2b(f.w);
            *(s16x4*)&As[row][ac] = h;
        }
        #pragma unroll
        for (int p = 0; p < 2; ++p) {
            int n = br + p * 64, gn = n0 + n;
            s16x8 h = (s16x8){0,0,0,0,0,0,0,0};
            if (gn < N) {
                float4 f0 = *(const float4*)(Bv + (long)gn * K + k0 + bc);
                float4 f1 = *(const float4*)(Bv + (long)gn * K + k0 + bc + 4);
                h[0]=f2b(f0.x); h[1]=f2b(f0.y); h[2]=f2b(f0.z); h[3]=f2b(f0.w);
                h[4]=f2b(f1.x); h[5]=f2b(f1.y); h[6]=f2b(f1.z); h[7]=f2b(f1.w);
            }
            *(s16x8*)&Bs[n][bc] = h;
        }
        __syncthreads();
        s16x8 af[4], bf[4];
        #pragma unroll
        for (int i = 0; i < 4; ++i) af[i] = *(const s16x8*)&As[wr*64 + i*16 + lr][kg*8];
        #pragma unroll
        for (int j = 0; j < 4; ++j) bf[j] = *(const s16x8*)&Bs[wc*64 + j*16 + lr][kg*8];
        #pragma unroll
        for (int i = 0; i < 4; ++i)
            #pragma unroll
            for (int j = 0; j < 4; ++j)
                acc[i][j] = __builtin_amdgcn_mfma_f32_16x16x32_bf16(af[i], bf[j], acc[i][j], 0, 0, 0);
        __syncthreads();
    }
    #pragma unroll
    for (int j = 0; j < 4; ++j) {
        int gcol = n0 + wc * 64 + j * 16 + lr;
        if (gcol >= N) continue;
        float bv = bias ? bias[gcol] : 0.f;
        #pragma unroll
        for (int i = 0; i < 4; ++i) {
            int grow0 = m0 + wr * 64 + i * 16 + kg * 4;
            #pragma unroll
            for (int qq = 0; qq < 4; ++qq) {
                int gr = grow0 + qq;
                if (gr >= M) continue;
                Cm[(long)gr * ldc + gcol] = acc[i][j][qq] + bv;
            }
        }
    }
}

// ---------------------------------------------------------------------------
// MFMA flash attention, KVBLK=128. grid (16, H, B), 4 waves, 64 q-rows/block.
// T14 async reg-prefetch; T13 defer-max; Q pre-scaled by 1/32 (exact).
// qkvb: [M,3072] bf16 (q|k|v, head h at col h*64). outb: [M,C] bf16.
// qc (nullable): [M,1024] bf16 split-K partial-2 for Q, summed in fp32.
// ---------------------------------------------------------------------------
template<bool CAUSAL>
__global__ __launch_bounds__(256) void fattn_kernel(
    const __hip_bfloat16* __restrict__ qkvb,
    const __hip_bfloat16* __restrict__ qc,
    __hip_bfloat16* __restrict__ outb)
{
    __shared__ short Ks[128][72];        // [s][d]
    __shared__ short Vt[64][136];        // [d][s]
    __shared__ short Ps[4][16][136];     // per-wave [q][s]

    const int q0 = blockIdx.x * 64;
    const int h = blockIdx.y, b = blockIdx.z;
    const int tid = threadIdx.x;
    const int lane = tid & 63, w = tid >> 6;
    const int lr = lane & 15, lg = lane >> 4;

    const long base = (long)b * TT * 3072;
    const __hip_bfloat16* Kg = qkvb + base + 1024 + h * 64;
    const __hip_bfloat16* Vg = qkvb + base + 2048 + h * 64;

    s16x8 qf[2];
    {
        int qr = q0 + w * 16 + lr;
        #pragma unroll
        for (int kc = 0; kc < 2; ++kc) {
            s16x8 hv = (s16x8){0,0,0,0,0,0,0,0};
            if (qr < TT) {
                hv = *(const s16x8*)(qkvb + base + (long)qr * 3072 + h * 64 + kc * 32 + lg * 8);
                if (qc) {
                    s16x8 h2 = *(const s16x8*)(qc + ((long)b * TT + qr) * CC + h * 64 + kc * 32 + lg * 8);
                    #pragma unroll
                    for (int e = 0; e < 8; ++e)
                        hv[e] = f2b((b2f(hv[e]) + b2f(h2[e])) * 0.03125f);
                } else {
                    #pragma unroll
                    for (int e = 0; e < 8; ++e)
                        hv[e] = f2b(b2f(hv[e]) * 0.03125f);
                }
            }
            qf[kc] = hv;
        }
    }

    f32x4 acc[4];
    #pragma unroll
    for (int jd = 0; jd < 4; ++jd) acc[jd] = (f32x4){0.f, 0.f, 0.f, 0.f};
    float mrun[4] = {-3.0e38f, -3.0e38f, -3.0e38f, -3.0e38f};
    float lrun[4] = {0.f, 0.f, 0.f, 0.f};

    const int send = CAUSAL ? min(TT, q0 + 64) : TT;
    const int nt = (send + 127) >> 7;
    const int sr4 = (tid >> 3) * 4;        // rows sr4..sr4+3
    const int dcc = (tid & 7) * 8;         // col chunk

    s16x8 kreg[4], vreg[4];
    auto loadkv = [&](int t) {
        int sbase = t * 128;
        #pragma unroll
        for (int rr = 0; rr < 4; ++rr) {
            int sg = sbase + sr4 + rr;
            if (sg < TT) {
                kreg[rr] = *(const s16x8*)(Kg + (long)sg * 3072 + dcc);
                vreg[rr] = *(const s16x8*)(Vg + (long)sg * 3072 + dcc);
            } else {
                kreg[rr] = (s16x8){0,0,0,0,0,0,0,0};
                vreg[rr] = (s16x8){0,0,0,0,0,0,0,0};
            }
        }
    };

    loadkv(0);
    for (int ti = 0; ti < nt; ++ti) {
        const int s0 = ti * 128;
        SCHED0; SBAR; SCHED0;          // prev tile's LDS reads done (all waves)
        #pragma unroll
        for (int rr = 0; rr < 4; ++rr)
            *(s16x8*)&Ks[sr4 + rr][dcc] = kreg[rr];
        #pragma unroll
        for (int pr = 0; pr < 2; ++pr) {
            #pragma unroll
            for (int e = 0; e < 8; ++e) {
                unsigned pack = (unsigned)(unsigned short)vreg[2*pr][e]
                              | ((unsigned)(unsigned short)vreg[2*pr + 1][e] << 16);
                *(unsigned*)&Vt[dcc + e][sr4 + 2*pr] = pack;
            }
        }
        if (ti + 1 < nt) loadkv(ti + 1);   // issue next tile's loads early
        SCHED0; LGKMCNT0; SCHED0; SBAR; SCHED0;   // LDS writes visible

        // ---- S = (Q/32) K^T over 128 kv cols ----
        f32x4 sf[8];
        __builtin_amdgcn_s_setprio(1);
        #pragma unroll
        for (int j = 0; j < 8; ++j) {
            f32x4 z = (f32x4){0.f, 0.f, 0.f, 0.f};
            #pragma unroll
            for (int kc = 0; kc < 2; ++kc) {
                s16x8 kf = *(const s16x8*)&Ks[j * 16 + lr][kc * 32 + lg * 8];
                z = __builtin_amdgcn_mfma_f32_16x16x32_bf16(qf[kc], kf, z, 0, 0, 0);
            }
            sf[j] = z;
        }
        __builtin_amdgcn_s_setprio(0);

        float mloc[4] = {-3.0e38f, -3.0e38f, -3.0e38f, -3.0e38f};
        #pragma unroll
        for (int j = 0; j < 8; ++j) {
            int sg = s0 + j * 16 + lr;
            #pragma unroll
            for (int r = 0; r < 4; ++r) {
                float sc = sf[j][r];
                int qg = q0 + w * 16 + lg * 4 + r;
                if ((CAUSAL && sg > qg) || sg >= TT) sc = -3.0e38f;
                sf[j][r] = sc;
                mloc[r] = fmaxf(mloc[r], sc);
            }
        }
        #pragma unroll
        for (int r = 0; r < 4; ++r)
            #pragma unroll
            for (int off = 1; off < 16; off <<= 1)
                mloc[r] = fmaxf(mloc[r], __shfl_xor(mloc[r], off));

        // ---- T13 defer-max: rescale only if some row's max grew > 8 ----
        bool grow = false;
        #pragma unroll
        for (int r = 0; r < 4; ++r)
            grow = grow || (mloc[r] > mrun[r] + 8.0f);
        if (__any((int)grow)) {
            #pragma unroll
            for (int r = 0; r < 4; ++r) {
                float mn = fmaxf(mrun[r], mloc[r]);
                float corr = __expf(mrun[r] - mn);
                mrun[r] = mn;
                lrun[r] *= corr;
                #pragma unroll
                for (int jd = 0; jd < 4; ++jd) acc[jd][r] *= corr;
            }
        }

        float psum[4] = {0.f, 0.f, 0.f, 0.f};
        #pragma unroll
        for (int j = 0; j < 8; ++j) {
            #pragma unroll
            for (int r = 0; r < 4; ++r) {
                float p = __expf(sf[j][r] - mrun[r]);
                psum[r] += p;
                Ps[w][lg * 4 + r][j * 16 + lr] = f2b(p);
            }
        }
        #pragma unroll
        for (int r = 0; r < 4; ++r) {
            #pragma unroll
            for (int off = 1; off < 16; off <<= 1)
                psum[r] += __shfl_xor(psum[r], off);
            lrun[r] += psum[r];
        }

        // ---- O += P @ V over K=128 ----
        __builtin_amdgcn_s_setprio(1);
        #pragma unroll
        for (int kc = 0; kc < 4; ++kc) {
            s16x8 pa = *(const s16x8*)&Ps[w][lr][kc * 32 + lg * 8];
            #pragma unroll
            for (int jd = 0; jd < 4; ++jd) {
                s16x8 bv = *(const s16x8*)&Vt[jd * 16 + lr][kc * 32 + lg * 8];
                acc[jd] = __builtin_amdgcn_mfma_f32_16x16x32_bf16(pa, bv, acc[jd], 0, 0, 0);
            }
        }
        __builtin_amdgcn_s_setprio(0);
        SCHED0; LGKMCNT0; SCHED0;      // my LDS reads complete before next write
    }

    #pragma unroll
    for (int r = 0; r < 4; ++r) {
        int qg = q0 + w * 16 + lg * 4 + r;
        if (qg >= TT) continue;
        float inv = 1.0f / lrun[r];
        #pragma unroll
        for (int jd = 0; jd < 4; ++jd)
            outb[((long)b * TT + qg) * CC + h * 64 + jd * 16 + lr] =
                __float2bfloat16(acc[jd][r] * inv);
    }
}

// ---------------------------------------------------------------------------
// LayerNorm from fp32 input (+optional residual), nullable fp32 out + bf16.
// ---------------------------------------------------------------------------
__global__ __launch_bounds__(256) void ln_kernel(
    const float* __restrict__ in, const float* __restrict__ res,
    const float* __restrict__ g, const float* __restrict__ b,
    float* __restrict__ out, __hip_bfloat16* __restrict__ outb)
{
    const int r = blockIdx.x, tid = threadIdx.x;
    __shared__ float sm[4];

    float4 xv = *(const float4*)(in + (long)r * CC + tid * 4);
    float s = xv.x + xv.y + xv.z + xv.w;
    #pragma unroll
    for (int o = 32; o > 0; o >>= 1) s += __shfl_xor(s, o);
    if ((tid & 63) == 0) sm[tid >> 6] = s;
    __syncthreads();
    const float mean = (sm[0] + sm[1] + sm[2] + sm[3]) * (1.0f / CC);
    __syncthreads();

    float4 d; d.x = xv.x - mean; d.y = xv.y - mean; d.z = xv.z - mean; d.w = xv.w - mean;
    float s2 = d.x * d.x + d.y * d.y + d.z * d.z + d.w * d.w;
    #pragma unroll
    for (int o = 32; o > 0; o >>= 1) s2 += __shfl_xor(s2, o);
    if ((tid & 63) == 0) sm[tid >> 6] = s2;
    __syncthreads();
    const float rstd = rsqrtf((sm[0] + sm[1] + sm[2] + sm[3]) * (1.0f / CC) + 1e-5f);

    float4 gv = *(const float4*)(g + tid * 4);
    float4 bv = *(const float4*)(b + tid * 4);
    float4 o;
    o.x = gv.x * d.x * rstd + bv.x; o.y = gv.y * d.y * rstd + bv.y;
    o.z = gv.z * d.z * rstd + bv.z; o.w = gv.w * d.w * rstd + bv.w;
    if (res) {
        float4 rv = *(const float4*)(res + (long)r * CC + tid * 4);
        o.x += rv.x; o.y += rv.y; o.z += rv.z; o.w += rv.w;
    }
    if (out) *(float4*)(out + (long)r * CC + tid * 4) = o;
    if (outb) {
        s16x4 h; h[0] = f2b(o.x); h[1] = f2b(o.y); h[2] = f2b(o.z); h[3] = f2b(o.w);
        *(s16x4*)(outb + (long)r * CC + tid * 4) = h;
    }
}

// ---------------------------------------------------------------------------
// LayerNorm from bf16 input pair (in + in2, summed in fp32) + fp32 residual,
// fp32 out + bf16 mirror.  in2 nullable.
// ---------------------------------------------------------------------------
__global__ __launch_bounds__(256) void lnb_kernel(
    const __hip_bfloat16* __restrict__ in, const __hip_bfloat16* __restrict__ in2,
    const float* __restrict__ res,
    const float* __restrict__ g, const float* __restrict__ b,
    float* __restrict__ out, __hip_bfloat16* __restrict__ outb)
{
    const int r = blockIdx.x, tid = threadIdx.x;
    __shared__ float sm[4];

    s16x4 hv = *(const s16x4*)((const short*)in + (long)r * CC + tid * 4);
    float4 xv;
    xv.x = b2f(hv[0]); xv.y = b2f(hv[1]); xv.z = b2f(hv[2]); xv.w = b2f(hv[3]);
    if (in2) {
        s16x4 h2 = *(const s16x4*)((const short*)in2 + (long)r * CC + tid * 4);
        xv.x += b2f(h2[0]); xv.y += b2f(h2[1]); xv.z += b2f(h2[2]); xv.w += b2f(h2[3]);
    }
    float s = xv.x + xv.y + xv.z + xv.w;
    #pragma unroll
    for (int o = 32; o > 0; o >>= 1) s += __shfl_xor(s, o);
    if ((tid & 63) == 0) sm[tid >> 6] = s;
    __syncthreads();
    const float mean = (sm[0] + sm[1] + sm[2] + sm[3]) * (1.0f / CC);
    __syncthreads();

    float4 d; d.x = xv.x - mean; d.y = xv.y - mean; d.z = xv.z - mean; d.w = xv.w - mean;
    float s2 = d.x * d.x + d.y * d.y + d.z * d.z + d.w * d.w;
    #pragma unroll
    for (int o = 32; o > 0; o >>= 1) s2 += __shfl_xor(s2, o);
    if ((tid & 63) == 0) sm[tid >> 6] = s2;
    __syncthreads();
    const float rstd = rsqrtf((sm[0] + sm[1] + sm[2] + sm[3]) * (1.0f / CC) + 1e-5f);

    float4 gv = *(const float4*)(g + tid * 4);
    float4 bv = *(const float4*)(b + tid * 4);
    float4 o;
    o.x = gv.x * d.x * rstd + bv.x; o.y = gv.y * d.y * rstd + bv.y;
    o.z = gv.z * d.z * rstd + bv.z; o.w = gv.w * d.w * rstd + bv.w;
    if (res) {
        float4 rv = *(const float4*)(res + (long)r * CC + tid * 4);
        o.x += rv.x; o.y += rv.y; o.z += rv.z; o.w += rv.w;
    }
    *(float4*)(out + (long)r * CC + tid * 4) = o;
    s16x4 hh; hh[0] = f2b(o.x); hh[1] = f2b(o.y); hh[2] = f2b(o.z); hh[3] = f2b(o.w);
    *(s16x4*)((short*)outb + (long)r * CC + tid * 4) = hh;
}

// ---------------------------------------------------------------------------
extern "C" void kernel_launch(void* const* d_in, const int* in_sizes, int n_in,
                              void* d_out, int out_size, void* d_ws, size_t ws_size,
                              hipStream_t stream)
{
    const int*   x      = (const int*)  d_in[0];
    const int*   y      = (const int*)  d_in[1];
    const float* wte    = (const float*)d_in[2];
    const float* wpe_x  = (const float*)d_in[3];
    const float* wpe_y  = (const float*)d_in[4];
    const float* eWq    = (const float*)d_in[5];
    const float* eWk    = (const float*)d_in[6];
    const float* eWv    = (const float*)d_in[7];
    const float* epw    = (const float*)d_in[8];
    const float* epb    = (const float*)d_in[9];
    const float* eln1g  = (const float*)d_in[10];
    const float* eln1b  = (const float*)d_in[11];
    const float* eln2g  = (const float*)d_in[12];
    const float* eln2b  = (const float*)d_in[13];
    const float* ew1    = (const float*)d_in[14];
    const float* eb1    = (const float*)d_in[15];
    const float* ew2    = (const float*)d_in[16];
    const float* eb2    = (const float*)d_in[17];
    const float* dsWq   = (const float*)d_in[18];
    const float* dsWk   = (const float*)d_in[19];
    const float* dsWv   = (const float*)d_in[20];
    const float* dspw   = (const float*)d_in[21];
    const float* dspb   = (const float*)d_in[22];
    const float* dcWq   = (const float*)d_in[23];
    const float* dcWk   = (const float*)d_in[24];
    const float* dcWv   = (const float*)d_in[25];
    const float* dcpw   = (const float*)d_in[26];
    const float* dcpb   = (const float*)d_in[27];
    const float* dln1g  = (const float*)d_in[28];
    const float* dln1b  = (const float*)d_in[29];
    const float* dln2g  = (const float*)d_in[30];
    const float* dln2b  = (const float*)d_in[31];
    const float* dln3g  = (const float*)d_in[32];
    const float* dln3b  = (const float*)d_in[33];
    const float* dw1    = (const float*)d_in[34];
    const float* db1    = (const float*)d_in[35];
    const float* dw2    = (const float*)d_in[36];
    const float* db2    = (const float*)d_in[37];
    const float* lnfg   = (const float*)d_in[38];
    const float* lnfb   = (const float*)d_in[39];
    const float* lm_b   = (const float*)d_in[40];

    float* out = (float*)d_out;

    // ---- workspace carve-up ----
    const size_t MCp = (size_t)MP * CC;
    float* enc = (float*)d_ws;
    float* dec = enc + MCp;
    float* t0  = dec + MCp;
    __hip_bfloat16* encb = (__hip_bfloat16*)(t0 + MCp);
    __hip_bfloat16* decb = encb + MCp;
    __hip_bfloat16* t0b  = decb + MCp;
    __hip_bfloat16* t0c  = t0b + MCp;                    // split-K partial 2
    __hip_bfloat16* a0b  = t0c + MCp;
    __hip_bfloat16* qkvb = a0b + MCp;                    // [MP][3072]
    __hip_bfloat16* qcb  = qkvb + (size_t)MP * 3072;     // [MP][1024] q partial 2
    __hip_bfloat16* ffb  = qcb + MCp;                    // [MP][FFD]
    __hip_bfloat16* wteb = ffb + (size_t)MP * FFD;       // [VP][C]
    // big-mode weight blocks
    __hip_bfloat16* eQKVw = wteb + (size_t)VP * CC;      // [L][3072][C]
    __hip_bfloat16* ePWw  = eQKVw + (size_t)LL * 3072 * CC;
    __hip_bfloat16* eW1w  = ePWw  + (size_t)LL * CC * CC;     // [L][FFD][C]
    __hip_bfloat16* eW2w  = eW1w  + (size_t)LL * FFD * CC;    // [L][C][FFD]
    __hip_bfloat16* sQKVw = eW2w  + (size_t)LL * CC * FFD;
    __hip_bfloat16* sPWw  = sQKVw + (size_t)LL * 3072 * CC;
    __hip_bfloat16* cQKVw = sPWw  + (size_t)LL * CC * CC;
    __hip_bfloat16* cPWw  = cQKVw + (size_t)LL * 3072 * CC;
    __hip_bfloat16* dW1w  = cPWw  + (size_t)LL * CC * CC;
    __hip_bfloat16* dW2w  = dW1w  + (size_t)LL * FFD * CC;
    __hip_bfloat16* bigEnd = dW2w + (size_t)LL * CC * FFD;
    // small-mode: per-use conversion buffer where eQKVw starts
    __hip_bfloat16* wb = eQKVw;
    const size_t needBig   = (size_t)((char*)bigEnd - (char*)d_ws);
    const size_t needSmall = (size_t)((char*)(wb + (size_t)FFD * CC) - (char*)d_ws);
    const size_t needWteb  = (size_t)((char*)eQKVw - (char*)d_ws);
    const bool big     = (ws_size >= needBig);
    const bool useWteb = (ws_size >= needWteb) &&
                         (big || ws_size >= needSmall);

    const int QT = (TT + 63) / 64;     // 16 q-tiles
    const dim3 tblk(32, 8);

    // bf16-out GEMM launcher, non-split.  64x128 up to N=3072 (>=3 blocks/CU),
    // 128x128 beyond (FFN1, logits).
    auto gemm = [&](const __hip_bfloat16* A, const __hip_bfloat16* B,
                    const float* bias, __hip_bfloat16* Cb,
                    int N_, int K_, int ldc, bool relu) {
        if (N_ <= 3072) {            // 64x128
            const int GMv = MP / 64;
            int nwg = GMv * ((N_ + 127) / 128);
            if (relu) mgemm2_kernel<2, true , 64, 128, false><<<nwg, 256, 0, stream>>>(A, B, bias, nullptr, Cb, nullptr, MM, N_, K_, K_, ldc, ldc, GMv);
            else      mgemm2_kernel<2, false, 64, 128, false><<<nwg, 256, 0, stream>>>(A, B, bias, nullptr, Cb, nullptr, MM, N_, K_, K_, ldc, ldc, GMv);
        } else {                     // 128x128
            const int GMv = MP / 128;
            int nwg = GMv * ((N_ + 127) / 128);
            if (relu) mgemm2_kernel<2, true , 128, 128, false><<<nwg, 256, 0, stream>>>(A, B, bias, nullptr, Cb, nullptr, MM, N_, K_, K_, ldc, ldc, GMv);
            else      mgemm2_kernel<2, false, 128, 128, false><<<nwg, 256, 0, stream>>>(A, B, bias, nullptr, Cb, nullptr, MM, N_, K_, K_, ldc, ldc, GMv);
        }
    };
    // split-K=2 launcher for N=1024 GEMMs (no relu); one launch, doubled grid.
    auto gemm_sk = [&](const __hip_bfloat16* A, const __hip_bfloat16* B,
                       const float* bias, __hip_bfloat16* Cb, __hip_bfloat16* Cb2,
                       int K_, int ldc, int ldc2) {
        const int GMv = MP / 64;
        int nwg = 2 * GMv * (CC / 128);
        mgemm2_kernel<2, false, 64, 128, true><<<nwg, 256, 0, stream>>>(
            A, B, bias, nullptr, Cb, Cb2, MM, CC, K_ / 2, K_, ldc, ldc2, GMv);
    };

    if (useWteb) {
        long n = (long)VV * CC;
        cvtb_kernel<<<(int)((n / 8 + 255) / 256), 256, 0, stream>>>(wte, wteb, n);
    }

    if (big) {
        // ---- all weight conversions up-front ----
        const long sWH = (long)CC * HSZ;            // per-(l,h) input stride
        const long oA = (long)3072 * CC;            // per-layer qkv out stride
        const long oB = (long)HSZ * CC;             // per-head out stride
        dim3 gq(HSZ / 32, CC / 32, LL * HH);
        tcvt_kernel<<<gq, tblk, 0, stream>>>(eWq, eQKVw,             CC, HSZ, sWH, oA, oB, HH);
        tcvt_kernel<<<gq, tblk, 0, stream>>>(eWk, eQKVw + CC * CC,   CC, HSZ, sWH, oA, oB, HH);
        tcvt_kernel<<<gq, tblk, 0, stream>>>(eWv, eQKVw + 2*CC*CC,   CC, HSZ, sWH, oA, oB, HH);
        tcvt_kernel<<<gq, tblk, 0, stream>>>(dsWq, sQKVw,            CC, HSZ, sWH, oA, oB, HH);
        tcvt_kernel<<<gq, tblk, 0, stream>>>(dsWk, sQKVw + CC * CC,  CC, HSZ, sWH, oA, oB, HH);
        tcvt_kernel<<<gq, tblk, 0, stream>>>(dsWv, sQKVw + 2*CC*CC,  CC, HSZ, sWH, oA, oB, HH);
        tcvt_kernel<<<gq, tblk, 0, stream>>>(dcWq, cQKVw,            CC, HSZ, sWH, oA, oB, HH);
        tcvt_kernel<<<gq, tblk, 0, stream>>>(dcWk, cQKVw + CC * CC,  CC, HSZ, sWH, oA, oB, HH);
        tcvt_kernel<<<gq, tblk, 0, stream>>>(dcWv, cQKVw + 2*CC*CC,  CC, HSZ, sWH, oA, oB, HH);
        dim3 gp(CC / 32, CC / 32, LL);
        tcvt_kernel<<<gp, tblk, 0, stream>>>(epw,  ePWw, CC, CC, (long)CC*CC, (long)CC*CC, 0, 1);
        tcvt_kernel<<<gp, tblk, 0, stream>>>(dspw, sPWw, CC, CC, (long)CC*CC, (long)CC*CC, 0, 1);
        tcvt_kernel<<<gp, tblk, 0, stream>>>(dcpw, cPWw, CC, CC, (long)CC*CC, (long)CC*CC, 0, 1);
        dim3 g1(FFD / 32, CC / 32, LL);
        tcvt_kernel<<<g1, tblk, 0, stream>>>(ew1, eW1w, CC, FFD, (long)CC*FFD, (long)FFD*CC, 0, 1);
        tcvt_kernel<<<g1, tblk, 0, stream>>>(dw1, dW1w, CC, FFD, (long)CC*FFD, (long)FFD*CC, 0, 1);
        dim3 g2(CC / 32, FFD / 32, LL);
        tcvt_kernel<<<g2, tblk, 0, stream>>>(ew2, eW2w, FFD, CC, (long)FFD*CC, (long)CC*FFD, 0, 1);
        tcvt_kernel<<<g2, tblk, 0, stream>>>(dw2, dW2w, FFD, CC, (long)FFD*CC, (long)CC*FFD, 0, 1);
    }

    // small-mode per-use converters
    auto cvt_qkv = [&](const float* Wq, const float* Wk, const float* Wv) {
        dim3 g(HSZ / 32, CC / 32, HH);
        tcvt_kernel<<<g, tblk, 0, stream>>>(Wq, wb,             CC, HSZ, (long)CC*HSZ, (long)HSZ*CC, 0, 1);
        tcvt_kernel<<<g, tblk, 0, stream>>>(Wk, wb + CC*CC,     CC, HSZ, (long)CC*HSZ, (long)HSZ*CC, 0, 1);
        tcvt_kernel<<<g, tblk, 0, stream>>>(Wv, wb + 2*CC*CC,   CC, HSZ, (long)CC*HSZ, (long)HSZ*CC, 0, 1);
    };
    auto cvt_nt = [&](const float* W, int R, int S) {
        dim3 g(S / 32, R / 32, 1);
        tcvt_kernel<<<g, tblk, 0, stream>>>(W, wb, R, S, 0, 0, 0, 1);
    };

    // ---- encoder ----
    embed_kernel<<<MM, 256, 0, stream>>>(x, wte, wpe_x, enc, encb);
    for (int i = 0; i < LL; ++i) {
        const long cOff = (long)i * CC;
        const __hip_bfloat16 *Wqkv, *Wp, *W1, *W2;
        if (big) {
            Wqkv = eQKVw + (size_t)i * 3072 * CC;
            Wp   = ePWw  + (size_t)i * CC * CC;
            W1   = eW1w  + (size_t)i * FFD * CC;
            W2   = eW2w  + (size_t)i * CC * FFD;
        }
        if (!big) cvt_qkv(eWq + (long)i*HH*CC*HSZ, eWk + (long)i*HH*CC*HSZ, eWv + (long)i*HH*CC*HSZ), Wqkv = wb;
        gemm(encb, Wqkv, nullptr, qkvb, 3072, CC, 3072, false);
        fattn_kernel<false><<<dim3(QT, HH, BB), 256, 0, stream>>>(qkvb, nullptr, a0b);
        if (!big) cvt_nt(epw + (long)i*CC*CC, CC, CC), Wp = wb;
        gemm_sk(a0b, Wp, epb + cOff, t0b, t0c, CC, CC, CC);
        lnb_kernel<<<MM, 256, 0, stream>>>(t0b, t0c, enc, eln1g + cOff, eln1b + cOff, enc, encb);
        if (!big) cvt_nt(ew1 + (long)i*CC*FFD, CC, FFD), W1 = wb;
        gemm(encb, W1, eb1 + (long)i*FFD, ffb, FFD, CC, FFD, true);
        if (!big) cvt_nt(ew2 + (long)i*FFD*CC, FFD, CC), W2 = wb;
        gemm_sk(ffb, W2, eb2 + cOff, t0b, t0c, FFD, CC, CC);
        lnb_kernel<<<MM, 256, 0, stream>>>(t0b, t0c, enc, eln2g + cOff, eln2b + cOff, enc, encb);
    }

    // ---- decoder ----
    embed_kernel<<<MM, 256, 0, stream>>>(y, wte, wpe_y, dec, decb);
    for (int i = 0; i < LL; ++i) {
        const long cOff = (long)i * CC;
        const __hip_bfloat16 *Ws, *Wsp, *Wc, *Wcp, *W1, *W2;
        if (big) {
            Ws  = sQKVw + (size_t)i * 3072 * CC;
            Wsp = sPWw  + (size_t)i * CC * CC;
            Wc  = cQKVw + (size_t)i * 3072 * CC;
            Wcp = cPWw  + (size_t)i * CC * CC;
            W1  = dW1w  + (size_t)i * FFD * CC;
            W2  = dW2w  + (size_t)i * CC * FFD;
        }
        // masked self-attn
        if (!big) cvt_qkv(dsWq + (long)i*HH*CC*HSZ, dsWk + (long)i*HH*CC*HSZ, dsWv + (long)i*HH*CC*HSZ), Ws = wb;
        gemm(decb, Ws, nullptr, qkvb, 3072, CC, 3072, false);
        fattn_kernel<true><<<dim3(QT, HH, BB), 256, 0, stream>>>(qkvb, nullptr, a0b);
        if (!big) cvt_nt(dspw + (long)i*CC*CC, CC, CC), Wsp = wb;
        gemm_sk(a0b, Wsp, dspb + cOff, t0b, t0c, CC, CC, CC);
        lnb_kernel<<<MM, 256, 0, stream>>>(t0b, t0c, dec, dln1g + cOff, dln1b + cOff, dec, decb);
        // cross-attn: q from dec (split-K), k/v from enc
        if (!big) cvt_qkv(dcWq + (long)i*HH*CC*HSZ, dcWk + (long)i*HH*CC*HSZ, dcWv + (long)i*HH*CC*HSZ), Wc = wb;
        gemm_sk(decb, Wc, nullptr, qkvb, qcb, CC, 3072, CC);
        gemm(encb, Wc + (size_t)CC * CC, nullptr, qkvb + CC, 2048, CC, 3072, false);
        fattn_kernel<false><<<dim3(QT, HH, BB), 256, 0, stream>>>(qkvb, qcb, a0b);
        if (!big) cvt_nt(dcpw + (long)i*CC*CC, CC, CC), Wcp = wb;
        gemm_sk(a0b, Wcp, dcpb + cOff, t0b, t0c, CC, CC, CC);
        lnb_kernel<<<MM, 256, 0, stream>>>(t0b, t0c, dec, dln2g + cOff, dln2b + cOff, dec, decb);
        // ffn
        if (!big) cvt_nt(dw1 + (long)i*CC*FFD, CC, FFD), W1 = wb;
        gemm(decb, W1, db1 + (long)i*FFD, ffb, FFD, CC, FFD, true);
        if (!big) cvt_nt(dw2 + (long)i*FFD*CC, FFD, CC), W2 = wb;
        gemm_sk(ffb, W2, db2 + cOff, t0b, t0c, FFD, CC, CC);
        lnb_kernel<<<MM, 256, 0, stream>>>(t0b, t0c, dec, dln3g + cOff, dln3b + cOff, dec, decb);
    }

    // ---- final LN + logits (M-split halves, 128x128 tile — r12 optimum) ----
    ln_kernel<<<MM, 256, 0, stream>>>(dec, nullptr, lnfg, lnfb,
                                      useWteb ? nullptr : t0, t0b);
    if (useWteb) {
        const int GMv = 1024 / 128;                 // 8 m-tiles per half
        const int nwg = GMv * ((VV + 127) / 128);
        mgemm2_kernel<0, false, 128, 128, false><<<nwg, 256, 0, stream>>>(
            t0b, wteb, lm_b, out, nullptr, nullptr, 1024, VV, CC, CC, VV, VV, GMv);
        mgemm2_kernel<0, false, 128, 128, false><<<nwg, 256, 0, stream>>>(
            t0b + (size_t)1024 * CC, wteb, lm_b, out + (size_t)1024 * VV, nullptr, nullptr,
            MM - 1024, VV, CC, CC, VV, VV, GMv);
    } else {
        dim3 grid((VV + 127) / 128, MP / 128);
        mgemm_f32b_kernel<<<grid, 256, 0, stream>>>(t0, wte, lm_b, out, MM, VV, CC, VV);
    }
}

// Round 18
// 2988.503 us; speedup vs baseline: 1.0088x; 1.0088x over previous
//
#include <hip/hip_runtime.h>
#include <hip/hip_bf16.h>

#define BB 2
#define TT 1023
#define CC 1024
#define HH 16
#define HSZ 64
#define LL 6
#define FFD 4096
#define VV 50258
#define MM (BB*TT)   // 2046
#define MP 2048      // padded row count
#define VP 50304     // padded vocab (multiple of 128)

typedef __attribute__((ext_vector_type(4))) float  f32x4;
typedef __attribute__((ext_vector_type(8))) short  s16x8;
typedef __attribute__((ext_vector_type(4))) short  s16x4;

#define SCHED0   __builtin_amdgcn_sched_barrier(0)
#define SBAR     __builtin_amdgcn_s_barrier()
#define LGKMCNT0 asm volatile("s_waitcnt lgkmcnt(0)" ::: "memory")

__device__ __forceinline__ short f2b(float x) {
    __hip_bfloat16 h = __float2bfloat16(x);
    short s;
    __builtin_memcpy(&s, &h, 2);
    return s;
}
__device__ __forceinline__ float b2f(short s) {
    unsigned u = ((unsigned)(unsigned short)s) << 16;
    float f;
    __builtin_memcpy(&f, &u, 4);
    return f;
}

__device__ __forceinline__ void gld16(const void* g, void* l) {
    __builtin_amdgcn_global_load_lds(
        (__attribute__((address_space(1))) const void*)g,
        (__attribute__((address_space(3))) void*)l, 16, 0, 0);
}

// ---------------------------------------------------------------------------
// Embedding: fp32 + bf16 mirror
// ---------------------------------------------------------------------------
__global__ __launch_bounds__(256) void embed_kernel(
    const int* __restrict__ ids, const float* __restrict__ wte,
    const float* __restrict__ wpe, float* __restrict__ out,
    __hip_bfloat16* __restrict__ outb)
{
    int r = blockIdx.x;
    int t = r % TT;
    long id = ids[r];
    int c = threadIdx.x * 4;
    float4 a = *(const float4*)(wte + id * (long)CC + c);
    float4 p = *(const float4*)(wpe + (long)t * CC + c);
    float4 o; o.x = a.x + p.x; o.y = a.y + p.y; o.z = a.z + p.z; o.w = a.w + p.w;
    *(float4*)(out + (long)r * CC + c) = o;
    s16x4 h; h[0] = f2b(o.x); h[1] = f2b(o.y); h[2] = f2b(o.z); h[3] = f2b(o.w);
    *(s16x4*)(outb + (long)r * CC + c) = h;
}

// ---------------------------------------------------------------------------
// Elementwise fp32 -> bf16
// ---------------------------------------------------------------------------
__global__ __launch_bounds__(256) void cvtb_kernel(
    const float* __restrict__ in, __hip_bfloat16* __restrict__ out, long n)
{
    long i = ((long)blockIdx.x * 256 + threadIdx.x) * 8;
    if (i >= n) return;
    float4 f0 = *(const float4*)(in + i);
    float4 f1 = *(const float4*)(in + i + 4);
    s16x8 h;
    h[0]=f2b(f0.x); h[1]=f2b(f0.y); h[2]=f2b(f0.z); h[3]=f2b(f0.w);
    h[4]=f2b(f1.x); h[5]=f2b(f1.y); h[6]=f2b(f1.z); h[7]=f2b(f1.w);
    *(s16x8*)(out + i) = h;
}

// ---------------------------------------------------------------------------
// Transpose + fp32->bf16: in [R][S] fp32 -> out [S][R] bf16, batched over z.
// ---------------------------------------------------------------------------
__global__ __launch_bounds__(256) void tcvt_kernel(
    const float* __restrict__ in, __hip_bfloat16* __restrict__ out,
    int R, int S, long inZ, long outZa, long outZb, int zdiv)
{
    int z = blockIdx.z;
    in  += (long)z * inZ;
    out += (long)(z / zdiv) * outZa + (long)(z % zdiv) * outZb;
    __shared__ float tile[32][33];
    int s0 = blockIdx.x * 32, r0 = blockIdx.y * 32;
    int tx = threadIdx.x, ty = threadIdx.y;
    #pragma unroll
    for (int i = 0; i < 4; ++i)
        tile[ty + i * 8][tx] = in[(long)(r0 + ty + i * 8) * S + s0 + tx];
    __syncthreads();
    #pragma unroll
    for (int i = 0; i < 4; ++i)
        out[(long)(s0 + ty + i * 8) * R + r0 + tx] =
            __float2bfloat16(tile[tx][ty + i * 8]);
}

// ---------------------------------------------------------------------------
// bf16 MFMA GEMM, T3+T4 pipelined, T2-swizzled, XCD-swizzled.
// Tile (BM,BN) in {(128,128),(64,128)} - r12 local optimum.
// SPLITK: single launch, doubled grid; block half ks reduces K over
// [ks*K, ks*K+K) of Kstride-long rows; ks=0 -> Cb/ldc (with bias),
// ks=1 -> Cb2/ldc2.  Consumer sums the two bf16 partials in fp32.
// 3 LDS buffers, 2-deep prefetch, counted vmcnt (2L/L/0), raw s_barrier,
// setprio around MFMA.
// WMODE: 0 = fp32 out (float2-coalesced), 2 = bf16 out (b128-coalesced).
// ---------------------------------------------------------------------------
template<int WMODE, bool RELU, int BM, int BN, bool SPLITK>
__global__ __launch_bounds__(256) void mgemm2_kernel(
    const __hip_bfloat16* __restrict__ A, const __hip_bfloat16* __restrict__ B,
    const float* __restrict__ bias, float* __restrict__ Cm,
    __hip_bfloat16* __restrict__ Cb, __hip_bfloat16* __restrict__ Cb2,
    int M, int N, int K, int Kstride, int ldc, int ldc2, int GM)
{
    constexpr int ASZ  = BM * 32;
    constexpr int BSZ  = BN * 32;
    constexpr int BUF  = ASZ + BSZ;
    constexpr int WROW = BM / 2;
    constexpr int WCOL = BN / 2;
    constexpr int NI   = WROW / 16;
    constexpr int NJ   = WCOL / 16;
    constexpr int NAC  = BM / 64;          // A chunks per wave
    constexpr int NBC  = BN / 64;          // B chunks per wave
    constexpr int L    = NAC + NBC;        // gld16 per thread per stage
    __shared__ short LDS[3 * BUF];

    // bijective XCD swizzle + m-fastest decode
    const int nwg = gridDim.x;
    const int bid = blockIdx.x;
    const int q = nwg >> 3, r = nwg & 7;
    const int xcd = bid & 7, lid = bid >> 3;
    int swz = (xcd < r) ? xcd * (q + 1) + lid
                        : r * (q + 1) + (xcd - r) * q + lid;
    int ks = 0;
    if (SPLITK) {
        const int hN = nwg >> 1;
        ks = (swz >= hN);
        swz -= ks * hN;
    }
    const int m0 = (swz % GM) * BM;
    const int n0 = (swz / GM) * BN;

    const int tid  = threadIdx.x;
    const int lane = tid & 63, w = tid >> 6;
    const int wr = w >> 1, wc = w & 1;
    const int lr = lane & 15, kg = lane >> 4;

    const __hip_bfloat16* Abase = A + (long)m0 * Kstride + (SPLITK ? ks * K : 0);
    const __hip_bfloat16* Bbase = B + (long)n0 * Kstride + (SPLITK ? ks * K : 0);
    const float* biasU = (SPLITK && ks) ? nullptr : bias;
    __hip_bfloat16* CbU = (SPLITK && ks) ? Cb2 : Cb;
    const int ldcU = (SPLITK && ks) ? ldc2 : ldc;

    f32x4 acc[NI][NJ];
    #pragma unroll
    for (int i = 0; i < NI; ++i)
        #pragma unroll
        for (int j = 0; j < NJ; ++j)
            acc[i][j] = (f32x4){0.f, 0.f, 0.f, 0.f};

    const int srow = lane >> 2;
    const int scol = (((lane & 3) ^ ((lane >> 3) & 3))) * 8;   // swizzled src

    auto stage = [&](int db, long kofs) {
        short* Ad = &LDS[db * BUF];
        short* Bd = Ad + ASZ;
        #pragma unroll
        for (int p = 0; p < NAC; ++p) {
            int cc = p * 4 + w;
            long ro = (long)(cc * 16 + srow) * Kstride + kofs + scol;
            gld16(Abase + ro, Ad + cc * 512);
        }
        #pragma unroll
        for (int p = 0; p < NBC; ++p) {
            int cc = p * 4 + w;
            long ro = (long)(cc * 16 + srow) * Kstride + kofs + scol;
            gld16(Bbase + ro, Bd + cc * 512);
        }
    };
    const int rslot = (kg ^ ((lr >> 1) & 3)) * 8;

    auto compute = [&](int db) {
        const short* Ar = &LDS[db * BUF];
        const short* Br = Ar + ASZ;
        s16x8 af[NI], bf[NJ];
        #pragma unroll
        for (int i = 0; i < NI; ++i)
            af[i] = *(const s16x8*)&Ar[(wr * WROW + i * 16 + lr) * 32 + rslot];
        #pragma unroll
        for (int j = 0; j < NJ; ++j)
            bf[j] = *(const s16x8*)&Br[(wc * WCOL + j * 16 + lr) * 32 + rslot];
        __builtin_amdgcn_s_setprio(1);
        #pragma unroll
        for (int i = 0; i < NI; ++i)
            #pragma unroll
            for (int j = 0; j < NJ; ++j)
                acc[i][j] = __builtin_amdgcn_mfma_f32_16x16x32_bf16(
                    af[i], bf[j], acc[i][j], 0, 0, 0);
        __builtin_amdgcn_s_setprio(0);
    };

    const int nt = K >> 5;
    stage(0, 0);
    if (nt > 1) stage(1, 32);
    int db = 0;
    for (int t = 0; t < nt; ++t) {
        if (t + 2 < nt) {
            stage((db + 2) % 3, (long)(t + 2) << 5);
            SCHED0;
            if constexpr (L == 4) asm volatile("s_waitcnt vmcnt(8)" ::: "memory");
            else asm volatile("s_waitcnt vmcnt(6)" ::: "memory");
            SCHED0;
        } else if (t + 1 < nt) {
            SCHED0;
            if constexpr (L == 4) asm volatile("s_waitcnt vmcnt(4)" ::: "memory");
            else asm volatile("s_waitcnt vmcnt(3)" ::: "memory");
            SCHED0;
        } else {
            SCHED0; asm volatile("s_waitcnt vmcnt(0)" ::: "memory"); SCHED0;
        }
        SBAR; SCHED0;
        compute(db);
        SCHED0; LGKMCNT0; SCHED0; SBAR; SCHED0;
        db = (db + 1) % 3;
    }

    // ---- epilogue: stage C tile through LDS for coalesced stores ----
    if (WMODE == 0) {
        float* LF = (float*)&LDS[0];
        if (BM == 128) {
            // [128][64] fp32 half-tiles
            #pragma unroll
            for (int h = 0; h < 2; ++h) {
                if (wc == h) {
                    #pragma unroll
                    for (int j = 0; j < NJ; ++j) {
                        int gcol = n0 + h * WCOL + j * 16 + lr;
                        float bv = (biasU && gcol < N) ? biasU[gcol] : 0.f;
                        #pragma unroll
                        for (int i = 0; i < NI; ++i) {
                            int row0 = wr * WROW + i * 16 + kg * 4;
                            #pragma unroll
                            for (int qq = 0; qq < 4; ++qq) {
                                float v = acc[i][j][qq] + bv;
                                if (RELU) v = fmaxf(v, 0.f);
                                LF[(row0 + qq) * 64 + j * 16 + lr] = v;
                            }
                        }
                    }
                }
                __syncthreads();
                #pragma unroll
                for (int i = 0; i < 16; ++i) {
                    int F = i * 256 + tid;
                    int row = F >> 5, col = (F & 31) * 2;
                    int gr = m0 + row, gc = n0 + h * 64 + col;
                    if (gr < M && gc < N)
                        *(float2*)(Cm + (long)gr * ldc + gc) = *(const float2*)&LF[row * 64 + col];
                }
                __syncthreads();
            }
        } else {
            // full [BM][BN] fp32 tile
            #pragma unroll
            for (int j = 0; j < NJ; ++j) {
                int gcol = n0 + wc * WCOL + j * 16 + lr;
                float bv = (biasU && gcol < N) ? biasU[gcol] : 0.f;
                #pragma unroll
                for (int i = 0; i < NI; ++i) {
                    int row0 = wr * WROW + i * 16 + kg * 4;
                    #pragma unroll
                    for (int qq = 0; qq < 4; ++qq) {
                        float v = acc[i][j][qq] + bv;
                        if (RELU) v = fmaxf(v, 0.f);
                        LF[(row0 + qq) * BN + wc * WCOL + j * 16 + lr] = v;
                    }
                }
            }
            __syncthreads();
            #pragma unroll
            for (int i = 0; i < BM * BN / 512; ++i) {
                int F = i * 256 + tid;
                int row = F / (BN / 2), col = (F % (BN / 2)) * 2;
                int gr = m0 + row, gc = n0 + col;
                if (gr < M && gc < N)
                    *(float2*)(Cm + (long)gr * ldc + gc) = *(const float2*)&LF[row * BN + col];
            }
        }
    } else {
        short* LS = (short*)&LDS[0];       // [BM][BN] bf16
        #pragma unroll
        for (int j = 0; j < NJ; ++j) {
            int gcol = n0 + wc * WCOL + j * 16 + lr;
            float bv = (biasU && gcol < N) ? biasU[gcol] : 0.f;
            #pragma unroll
            for (int i = 0; i < NI; ++i) {
                int row0 = wr * WROW + i * 16 + kg * 4;
                #pragma unroll
                for (int qq = 0; qq < 4; ++qq) {
                    float v = acc[i][j][qq] + bv;
                    if (RELU) v = fmaxf(v, 0.f);
                    LS[(row0 + qq) * BN + wc * WCOL + j * 16 + lr] = f2b(v);
                }
            }
        }
        __syncthreads();
        #pragma unroll
        for (int i = 0; i < BM * BN / 2048; ++i) {
            int F = i * 256 + tid;
            int row = F / (BN / 8), col = (F % (BN / 8)) * 8;
            int gr = m0 + row, gc = n0 + col;
            if (gr < M && gc < N)
                *(s16x8*)((short*)CbU + (long)gr * ldcU + gc) = *(const s16x8*)&LS[row * BN + col];
        }
    }
}

// ---------------------------------------------------------------------------
// Fallback fp32-B GEMM (logits only, if ws too small for bf16 wte mirror).
// ---------------------------------------------------------------------------
__global__ __launch_bounds__(256) void mgemm_f32b_kernel(
    const float* __restrict__ A, const float* __restrict__ Bv,
    const float* __restrict__ bias, float* __restrict__ Cm,
    int M, int N, int K, int ldc)
{
    __shared__ short As[128][40];
    __shared__ short Bs[128][40];
    const int tid  = threadIdx.x;
    const int lane = tid & 63, w = tid >> 6;
    const int wr = w >> 1, wc = w & 1;
    const int lr = lane & 15, kg = lane >> 4;
    const int m0 = blockIdx.y * 128, n0 = blockIdx.x * 128;
    const int ar = tid >> 3, ac = (tid & 7) * 4;
    const int br = tid >> 2, bc = (tid & 3) * 8;

    f32x4 acc[4][4];
    #pragma unroll
    for (int i = 0; i < 4; ++i)
        #pragma unroll
        for (int j = 0; j < 4; ++j)
            acc[i][j] = (f32x4){0.f, 0.f, 0.f, 0.f};

    for (int k0 = 0; k0 < K; k0 += 32) {
        #pragma unroll
        for (int p = 0; p < 4; ++p) {
            int row = ar + p * 32, gm = m0 + row;
            float4 f = {0.f, 0.f, 0.f, 0.f};
            if (gm < M) f = *(const float4*)(A + (long)gm * K + k0 + ac);
            s16x4 h; h[0] = f2b(f.x); h[1] = f2b(f.y); h[2] = f2b(f.z); h[3] = f2b(f.w);
            *(s16x4*)&As[row][ac] = h;
        }
        #pragma unroll
        for (int p = 0; p < 2; ++p) {
            int n = br + p * 64, gn = n0 + n;
            s16x8 h = (s16x8){0,0,0,0,0,0,0,0};
            if (gn < N) {
                float4 f0 = *(const float4*)(Bv + (long)gn * K + k0 + bc);
                float4 f1 = *(const float4*)(Bv + (long)gn * K + k0 + bc + 4);
                h[0]=f2b(f0.x); h[1]=f2b(f0.y); h[2]=f2b(f0.z); h[3]=f2b(f0.w);
                h[4]=f2b(f1.x); h[5]=f2b(f1.y); h[6]=f2b(f1.z); h[7]=f2b(f1.w);
            }
            *(s16x8*)&Bs[n][bc] = h;
        }
        __syncthreads();
        s16x8 af[4], bf[4];
        #pragma unroll
        for (int i = 0; i < 4; ++i) af[i] = *(const s16x8*)&As[wr*64 + i*16 + lr][kg*8];
        #pragma unroll
        for (int j = 0; j < 4; ++j) bf[j] = *(const s16x8*)&Bs[wc*64 + j*16 + lr][kg*8];
        #pragma unroll
        for (int i = 0; i < 4; ++i)
            #pragma unroll
            for (int j = 0; j < 4; ++j)
                acc[i][j] = __builtin_amdgcn_mfma_f32_16x16x32_bf16(af[i], bf[j], acc[i][j], 0, 0, 0);
        __syncthreads();
    }
    #pragma unroll
    for (int j = 0; j < 4; ++j) {
        int gcol = n0 + wc * 64 + j * 16 + lr;
        if (gcol >= N) continue;
        float bv = bias ? bias[gcol] : 0.f;
        #pragma unroll
        for (int i = 0; i < 4; ++i) {
            int grow0 = m0 + wr * 64 + i * 16 + kg * 4;
            #pragma unroll
            for (int qq = 0; qq < 4; ++qq) {
                int gr = grow0 + qq;
                if (gr >= M) continue;
                Cm[(long)gr * ldc + gcol] = acc[i][j][qq] + bv;
            }
        }
    }
}

// ---------------------------------------------------------------------------
// MFMA flash attention, KVBLK=128. grid (16, H, B), 4 waves, 64 q-rows/block.
// T14 async reg-prefetch; T13 defer-max; Q pre-scaled by 1/32 (exact).
// qkvb: [M,3072] bf16 (q|k|v, head h at col h*64). outb: [M,C] bf16.
// qc (nullable): [M,1024] bf16 split-K partial-2 for Q, summed in fp32.
// ---------------------------------------------------------------------------
template<bool CAUSAL>
__global__ __launch_bounds__(256) void fattn_kernel(
    const __hip_bfloat16* __restrict__ qkvb,
    const __hip_bfloat16* __restrict__ qc,
    __hip_bfloat16* __restrict__ outb)
{
    __shared__ short Ks[128][72];        // [s][d]
    __shared__ short Vt[64][136];        // [d][s]
    __shared__ short Ps[4][16][136];     // per-wave [q][s]

    const int q0 = blockIdx.x * 64;
    const int h = blockIdx.y, b = blockIdx.z;
    const int tid = threadIdx.x;
    const int lane = tid & 63, w = tid >> 6;
    const int lr = lane & 15, lg = lane >> 4;

    const long base = (long)b * TT * 3072;
    const __hip_bfloat16* Kg = qkvb + base + 1024 + h * 64;
    const __hip_bfloat16* Vg = qkvb + base + 2048 + h * 64;

    s16x8 qf[2];
    {
        int qr = q0 + w * 16 + lr;
        #pragma unroll
        for (int kc = 0; kc < 2; ++kc) {
            s16x8 hv = (s16x8){0,0,0,0,0,0,0,0};
            if (qr < TT) {
                hv = *(const s16x8*)(qkvb + base + (long)qr * 3072 + h * 64 + kc * 32 + lg * 8);
                if (qc) {
                    s16x8 h2 = *(const s16x8*)(qc + ((long)b * TT + qr) * CC + h * 64 + kc * 32 + lg * 8);
                    #pragma unroll
                    for (int e = 0; e < 8; ++e)
                        hv[e] = f2b((b2f(hv[e]) + b2f(h2[e])) * 0.03125f);
                } else {
                    #pragma unroll
                    for (int e = 0; e < 8; ++e)
                        hv[e] = f2b(b2f(hv[e]) * 0.03125f);
                }
            }
            qf[kc] = hv;
        }
    }

    f32x4 acc[4];
    #pragma unroll
    for (int jd = 0; jd < 4; ++jd) acc[jd] = (f32x4){0.f, 0.f, 0.f, 0.f};
    float mrun[4] = {-3.0e38f, -3.0e38f, -3.0e38f, -3.0e38f};
    float lrun[4] = {0.f, 0.f, 0.f, 0.f};

    const int send = CAUSAL ? min(TT, q0 + 64) : TT;
    const int nt = (send + 127) >> 7;
    const int sr4 = (tid >> 3) * 4;        // rows sr4..sr4+3
    const int dcc = (tid & 7) * 8;         // col chunk

    s16x8 kreg[4], vreg[4];
    auto loadkv = [&](int t) {
        int sbase = t * 128;
        #pragma unroll
        for (int rr = 0; rr < 4; ++rr) {
            int sg = sbase + sr4 + rr;
            if (sg < TT) {
                kreg[rr] = *(const s16x8*)(Kg + (long)sg * 3072 + dcc);
                vreg[rr] = *(const s16x8*)(Vg + (long)sg * 3072 + dcc);
            } else {
                kreg[rr] = (s16x8){0,0,0,0,0,0,0,0};
                vreg[rr] = (s16x8){0,0,0,0,0,0,0,0};
            }
        }
    };

    loadkv(0);
    for (int ti = 0; ti < nt; ++ti) {
        const int s0 = ti * 128;
        SCHED0; SBAR; SCHED0;          // prev tile's LDS reads done (all waves)
        #pragma unroll
        for (int rr = 0; rr < 4; ++rr)
            *(s16x8*)&Ks[sr4 + rr][dcc] = kreg[rr];
        #pragma unroll
        for (int pr = 0; pr < 2; ++pr) {
            #pragma unroll
            for (int e = 0; e < 8; ++e) {
                unsigned pack = (unsigned)(unsigned short)vreg[2*pr][e]
                              | ((unsigned)(unsigned short)vreg[2*pr + 1][e] << 16);
                *(unsigned*)&Vt[dcc + e][sr4 + 2*pr] = pack;
            }
        }
        if (ti + 1 < nt) loadkv(ti + 1);   // issue next tile's loads early
        SCHED0; LGKMCNT0; SCHED0; SBAR; SCHED0;   // LDS writes visible

        // ---- S = (Q/32) K^T over 128 kv cols ----
        f32x4 sf[8];
        __builtin_amdgcn_s_setprio(1);
        #pragma unroll
        for (int j = 0; j < 8; ++j) {
            f32x4 z = (f32x4){0.f, 0.f, 0.f, 0.f};
            #pragma unroll
            for (int kc = 0; kc < 2; ++kc) {
                s16x8 kf = *(const s16x8*)&Ks[j * 16 + lr][kc * 32 + lg * 8];
                z = __builtin_amdgcn_mfma_f32_16x16x32_bf16(qf[kc], kf, z, 0, 0, 0);
            }
            sf[j] = z;
        }
        __builtin_amdgcn_s_setprio(0);

        float mloc[4] = {-3.0e38f, -3.0e38f, -3.0e38f, -3.0e38f};
        #pragma unroll
        for (int j = 0; j < 8; ++j) {
            int sg = s0 + j * 16 + lr;
            #pragma unroll
            for (int r = 0; r < 4; ++r) {
                float sc = sf[j][r];
                int qg = q0 + w * 16 + lg * 4 + r;
                if ((CAUSAL && sg > qg) || sg >= TT) sc = -3.0e38f;
                sf[j][r] = sc;
                mloc[r] = fmaxf(mloc[r], sc);
            }
        }
        #pragma unroll
        for (int r = 0; r < 4; ++r)
            #pragma unroll
            for (int off = 1; off < 16; off <<= 1)
                mloc[r] = fmaxf(mloc[r], __shfl_xor(mloc[r], off));

        // ---- T13 defer-max: rescale only if some row's max grew > 8 ----
        bool grow = false;
        #pragma unroll
        for (int r = 0; r < 4; ++r)
            grow = grow || (mloc[r] > mrun[r] + 8.0f);
        if (__any((int)grow)) {
            #pragma unroll
            for (int r = 0; r < 4; ++r) {
                float mn = fmaxf(mrun[r], mloc[r]);
                float corr = __expf(mrun[r] - mn);
                mrun[r] = mn;
                lrun[r] *= corr;
                #pragma unroll
                for (int jd = 0; jd < 4; ++jd) acc[jd][r] *= corr;
            }
        }

        float psum[4] = {0.f, 0.f, 0.f, 0.f};
        #pragma unroll
        for (int j = 0; j < 8; ++j) {
            #pragma unroll
            for (int r = 0; r < 4; ++r) {
                float p = __expf(sf[j][r] - mrun[r]);
                psum[r] += p;
                Ps[w][lg * 4 + r][j * 16 + lr] = f2b(p);
            }
        }
        #pragma unroll
        for (int r = 0; r < 4; ++r) {
            #pragma unroll
            for (int off = 1; off < 16; off <<= 1)
                psum[r] += __shfl_xor(psum[r], off);
            lrun[r] += psum[r];
        }

        // ---- O += P @ V over K=128 ----
        __builtin_amdgcn_s_setprio(1);
        #pragma unroll
        for (int kc = 0; kc < 4; ++kc) {
            s16x8 pa = *(const s16x8*)&Ps[w][lr][kc * 32 + lg * 8];
            #pragma unroll
            for (int jd = 0; jd < 4; ++jd) {
                s16x8 bv = *(const s16x8*)&Vt[jd * 16 + lr][kc * 32 + lg * 8];
                acc[jd] = __builtin_amdgcn_mfma_f32_16x16x32_bf16(pa, bv, acc[jd], 0, 0, 0);
            }
        }
        __builtin_amdgcn_s_setprio(0);
        SCHED0; LGKMCNT0; SCHED0;      // my LDS reads complete before next write
    }

    #pragma unroll
    for (int r = 0; r < 4; ++r) {
        int qg = q0 + w * 16 + lg * 4 + r;
        if (qg >= TT) continue;
        float inv = 1.0f / lrun[r];
        #pragma unroll
        for (int jd = 0; jd < 4; ++jd)
            outb[((long)b * TT + qg) * CC + h * 64 + jd * 16 + lr] =
                __float2bfloat16(acc[jd][r] * inv);
    }
}

// ---------------------------------------------------------------------------
// LayerNorm from fp32 input (+optional residual), nullable fp32 out + bf16.
// ---------------------------------------------------------------------------
__global__ __launch_bounds__(256) void ln_kernel(
    const float* __restrict__ in, const float* __restrict__ res,
    const float* __restrict__ g, const float* __restrict__ b,
    float* __restrict__ out, __hip_bfloat16* __restrict__ outb)
{
    const int r = blockIdx.x, tid = threadIdx.x;
    __shared__ float sm[4];

    float4 xv = *(const float4*)(in + (long)r * CC + tid * 4);
    float s = xv.x + xv.y + xv.z + xv.w;
    #pragma unroll
    for (int o = 32; o > 0; o >>= 1) s += __shfl_xor(s, o);
    if ((tid & 63) == 0) sm[tid >> 6] = s;
    __syncthreads();
    const float mean = (sm[0] + sm[1] + sm[2] + sm[3]) * (1.0f / CC);
    __syncthreads();

    float4 d; d.x = xv.x - mean; d.y = xv.y - mean; d.z = xv.z - mean; d.w = xv.w - mean;
    float s2 = d.x * d.x + d.y * d.y + d.z * d.z + d.w * d.w;
    #pragma unroll
    for (int o = 32; o > 0; o >>= 1) s2 += __shfl_xor(s2, o);
    if ((tid & 63) == 0) sm[tid >> 6] = s2;
    __syncthreads();
    const float rstd = rsqrtf((sm[0] + sm[1] + sm[2] + sm[3]) * (1.0f / CC) + 1e-5f);

    float4 gv = *(const float4*)(g + tid * 4);
    float4 bv = *(const float4*)(b + tid * 4);
    float4 o;
    o.x = gv.x * d.x * rstd + bv.x; o.y = gv.y * d.y * rstd + bv.y;
    o.z = gv.z * d.z * rstd + bv.z; o.w = gv.w * d.w * rstd + bv.w;
    if (res) {
        float4 rv = *(const float4*)(res + (long)r * CC + tid * 4);
        o.x += rv.x; o.y += rv.y; o.z += rv.z; o.w += rv.w;
    }
    if (out) *(float4*)(out + (long)r * CC + tid * 4) = o;
    if (outb) {
        s16x4 h; h[0] = f2b(o.x); h[1] = f2b(o.y); h[2] = f2b(o.z); h[3] = f2b(o.w);
        *(s16x4*)(outb + (long)r * CC + tid * 4) = h;
    }
}

// ---------------------------------------------------------------------------
// LayerNorm from bf16 input pair (in + in2, summed in fp32) + fp32 residual,
// fp32 out + bf16 mirror.  in2 nullable.
// ---------------------------------------------------------------------------
__global__ __launch_bounds__(256) void lnb_kernel(
    const __hip_bfloat16* __restrict__ in, const __hip_bfloat16* __restrict__ in2,
    const float* __restrict__ res,
    const float* __restrict__ g, const float* __restrict__ b,
    float* __restrict__ out, __hip_bfloat16* __restrict__ outb)
{
    const int r = blockIdx.x, tid = threadIdx.x;
    __shared__ float sm[4];

    s16x4 hv = *(const s16x4*)((const short*)in + (long)r * CC + tid * 4);
    float4 xv;
    xv.x = b2f(hv[0]); xv.y = b2f(hv[1]); xv.z = b2f(hv[2]); xv.w = b2f(hv[3]);
    if (in2) {
        s16x4 h2 = *(const s16x4*)((const short*)in2 + (long)r * CC + tid * 4);
        xv.x += b2f(h2[0]); xv.y += b2f(h2[1]); xv.z += b2f(h2[2]); xv.w += b2f(h2[3]);
    }
    float s = xv.x + xv.y + xv.z + xv.w;
    #pragma unroll
    for (int o = 32; o > 0; o >>= 1) s += __shfl_xor(s, o);
    if ((tid & 63) == 0) sm[tid >> 6] = s;
    __syncthreads();
    const float mean = (sm[0] + sm[1] + sm[2] + sm[3]) * (1.0f / CC);
    __syncthreads();

    float4 d; d.x = xv.x - mean; d.y = xv.y - mean; d.z = xv.z - mean; d.w = xv.w - mean;
    float s2 = d.x * d.x + d.y * d.y + d.z * d.z + d.w * d.w;
    #pragma unroll
    for (int o = 32; o > 0; o >>= 1) s2 += __shfl_xor(s2, o);
    if ((tid & 63) == 0) sm[tid >> 6] = s2;
    __syncthreads();
    const float rstd = rsqrtf((sm[0] + sm[1] + sm[2] + sm[3]) * (1.0f / CC) + 1e-5f);

    float4 gv = *(const float4*)(g + tid * 4);
    float4 bv = *(const float4*)(b + tid * 4);
    float4 o;
    o.x = gv.x * d.x * rstd + bv.x; o.y = gv.y * d.y * rstd + bv.y;
    o.z = gv.z * d.z * rstd + bv.z; o.w = gv.w * d.w * rstd + bv.w;
    if (res) {
        float4 rv = *(const float4*)(res + (long)r * CC + tid * 4);
        o.x += rv.x; o.y += rv.y; o.z += rv.z; o.w += rv.w;
    }
    *(float4*)(out + (long)r * CC + tid * 4) = o;
    s16x4 hh; hh[0] = f2b(o.x); hh[1] = f2b(o.y); hh[2] = f2b(o.z); hh[3] = f2b(o.w);
    *(s16x4*)((short*)outb + (long)r * CC + tid * 4) = hh;
}

// ---------------------------------------------------------------------------
extern "C" void kernel_launch(void* const* d_in, const int* in_sizes, int n_in,
                              void* d_out, int out_size, void* d_ws, size_t ws_size,
                              hipStream_t stream)
{
    const int*   x      = (const int*)  d_in[0];
    const int*   y      = (const int*)  d_in[1];
    const float* wte    = (const float*)d_in[2];
    const float* wpe_x  = (const float*)d_in[3];
    const float* wpe_y  = (const float*)d_in[4];
    const float* eWq    = (const float*)d_in[5];
    const float* eWk    = (const float*)d_in[6];
    const float* eWv    = (const float*)d_in[7];
    const float* epw    = (const float*)d_in[8];
    const float* epb    = (const float*)d_in[9];
    const float* eln1g  = (const float*)d_in[10];
    const float* eln1b  = (const float*)d_in[11];
    const float* eln2g  = (const float*)d_in[12];
    const float* eln2b  = (const float*)d_in[13];
    const float* ew1    = (const float*)d_in[14];
    const float* eb1    = (const float*)d_in[15];
    const float* ew2    = (const float*)d_in[16];
    const float* eb2    = (const float*)d_in[17];
    const float* dsWq   = (const float*)d_in[18];
    const float* dsWk   = (const float*)d_in[19];
    const float* dsWv   = (const float*)d_in[20];
    const float* dspw   = (const float*)d_in[21];
    const float* dspb   = (const float*)d_in[22];
    const float* dcWq   = (const float*)d_in[23];
    const float* dcWk   = (const float*)d_in[24];
    const float* dcWv   = (const float*)d_in[25];
    const float* dcpw   = (const float*)d_in[26];
    const float* dcpb   = (const float*)d_in[27];
    const float* dln1g  = (const float*)d_in[28];
    const float* dln1b  = (const float*)d_in[29];
    const float* dln2g  = (const float*)d_in[30];
    const float* dln2b  = (const float*)d_in[31];
    const float* dln3g  = (const float*)d_in[32];
    const float* dln3b  = (const float*)d_in[33];
    const float* dw1    = (const float*)d_in[34];
    const float* db1    = (const float*)d_in[35];
    const float* dw2    = (const float*)d_in[36];
    const float* db2    = (const float*)d_in[37];
    const float* lnfg   = (const float*)d_in[38];
    const float* lnfb   = (const float*)d_in[39];
    const float* lm_b   = (const float*)d_in[40];

    float* out = (float*)d_out;

    // ---- workspace carve-up ----
    const size_t MCp = (size_t)MP * CC;
    float* enc = (float*)d_ws;
    float* dec = enc + MCp;
    float* t0  = dec + MCp;
    __hip_bfloat16* encb = (__hip_bfloat16*)(t0 + MCp);
    __hip_bfloat16* decb = encb + MCp;
    __hip_bfloat16* t0b  = decb + MCp;
    __hip_bfloat16* t0c  = t0b + MCp;                    // split-K partial 2
    __hip_bfloat16* a0b  = t0c + MCp;
    __hip_bfloat16* qkvb = a0b + MCp;                    // [MP][3072]
    __hip_bfloat16* qcb  = qkvb + (size_t)MP * 3072;     // [MP][1024] q partial 2
    __hip_bfloat16* ffb  = qcb + MCp;                    // [MP][FFD]
    __hip_bfloat16* wteb = ffb + (size_t)MP * FFD;       // [VP][C]
    // big-mode weight blocks
    __hip_bfloat16* eQKVw = wteb + (size_t)VP * CC;      // [L][3072][C]
    __hip_bfloat16* ePWw  = eQKVw + (size_t)LL * 3072 * CC;
    __hip_bfloat16* eW1w  = ePWw  + (size_t)LL * CC * CC;     // [L][FFD][C]
    __hip_bfloat16* eW2w  = eW1w  + (size_t)LL * FFD * CC;    // [L][C][FFD]
    __hip_bfloat16* sQKVw = eW2w  + (size_t)LL * CC * FFD;
    __hip_bfloat16* sPWw  = sQKVw + (size_t)LL * 3072 * CC;
    __hip_bfloat16* cQKVw = sPWw  + (size_t)LL * CC * CC;
    __hip_bfloat16* cPWw  = cQKVw + (size_t)LL * 3072 * CC;
    __hip_bfloat16* dW1w  = cPWw  + (size_t)LL * CC * CC;
    __hip_bfloat16* dW2w  = dW1w  + (size_t)LL * FFD * CC;
    __hip_bfloat16* bigEnd = dW2w + (size_t)LL * CC * FFD;
    // small-mode: per-use conversion buffer where eQKVw starts
    __hip_bfloat16* wb = eQKVw;
    const size_t needBig   = (size_t)((char*)bigEnd - (char*)d_ws);
    const size_t needSmall = (size_t)((char*)(wb + (size_t)FFD * CC) - (char*)d_ws);
    const size_t needWteb  = (size_t)((char*)eQKVw - (char*)d_ws);
    const bool big     = (ws_size >= needBig);
    const bool useWteb = (ws_size >= needWteb) &&
                         (big || ws_size >= needSmall);

    const int QT = (TT + 63) / 64;     // 16 q-tiles
    const dim3 tblk(32, 8);

    // bf16-out GEMM launcher, non-split (r12/r16 optimum tiles).
    auto gemm = [&](const __hip_bfloat16* A, const __hip_bfloat16* B,
                    const float* bias, __hip_bfloat16* Cb,
                    int N_, int K_, int ldc, bool relu) {
        if (N_ <= 2048) {            // 64x128
            const int GMv = MP / 64;
            int nwg = GMv * ((N_ + 127) / 128);
            if (relu) mgemm2_kernel<2, true , 64, 128, false><<<nwg, 256, 0, stream>>>(A, B, bias, nullptr, Cb, nullptr, MM, N_, K_, K_, ldc, ldc, GMv);
            else      mgemm2_kernel<2, false, 64, 128, false><<<nwg, 256, 0, stream>>>(A, B, bias, nullptr, Cb, nullptr, MM, N_, K_, K_, ldc, ldc, GMv);
        } else {                     // 128x128
            const int GMv = MP / 128;
            int nwg = GMv * ((N_ + 127) / 128);
            if (relu) mgemm2_kernel<2, true , 128, 128, false><<<nwg, 256, 0, stream>>>(A, B, bias, nullptr, Cb, nullptr, MM, N_, K_, K_, ldc, ldc, GMv);
            else      mgemm2_kernel<2, false, 128, 128, false><<<nwg, 256, 0, stream>>>(A, B, bias, nullptr, Cb, nullptr, MM, N_, K_, K_, ldc, ldc, GMv);
        }
    };
    // split-K=2 launcher for N=1024 GEMMs (no relu); one launch, doubled grid.
    auto gemm_sk = [&](const __hip_bfloat16* A, const __hip_bfloat16* B,
                       const float* bias, __hip_bfloat16* Cb, __hip_bfloat16* Cb2,
                       int K_, int ldc, int ldc2) {
        const int GMv = MP / 64;
        int nwg = 2 * GMv * (CC / 128);
        mgemm2_kernel<2, false, 64, 128, true><<<nwg, 256, 0, stream>>>(
            A, B, bias, nullptr, Cb, Cb2, MM, CC, K_ / 2, K_, ldc, ldc2, GMv);
    };

    if (useWteb) {
        long n = (long)VV * CC;
        cvtb_kernel<<<(int)((n / 8 + 255) / 256), 256, 0, stream>>>(wte, wteb, n);
    }

    if (big) {
        // ---- all weight conversions up-front ----
        const long sWH = (long)CC * HSZ;            // per-(l,h) input stride
        const long oA = (long)3072 * CC;            // per-layer qkv out stride
        const long oB = (long)HSZ * CC;             // per-head out stride
        dim3 gq(HSZ / 32, CC / 32, LL * HH);
        tcvt_kernel<<<gq, tblk, 0, stream>>>(eWq, eQKVw,             CC, HSZ, sWH, oA, oB, HH);
        tcvt_kernel<<<gq, tblk, 0, stream>>>(eWk, eQKVw + CC * CC,   CC, HSZ, sWH, oA, oB, HH);
        tcvt_kernel<<<gq, tblk, 0, stream>>>(eWv, eQKVw + 2*CC*CC,   CC, HSZ, sWH, oA, oB, HH);
        tcvt_kernel<<<gq, tblk, 0, stream>>>(dsWq, sQKVw,            CC, HSZ, sWH, oA, oB, HH);
        tcvt_kernel<<<gq, tblk, 0, stream>>>(dsWk, sQKVw + CC * CC,  CC, HSZ, sWH, oA, oB, HH);
        tcvt_kernel<<<gq, tblk, 0, stream>>>(dsWv, sQKVw + 2*CC*CC,  CC, HSZ, sWH, oA, oB, HH);
        tcvt_kernel<<<gq, tblk, 0, stream>>>(dcWq, cQKVw,            CC, HSZ, sWH, oA, oB, HH);
        tcvt_kernel<<<gq, tblk, 0, stream>>>(dcWk, cQKVw + CC * CC,  CC, HSZ, sWH, oA, oB, HH);
        tcvt_kernel<<<gq, tblk, 0, stream>>>(dcWv, cQKVw + 2*CC*CC,  CC, HSZ, sWH, oA, oB, HH);
        dim3 gp(CC / 32, CC / 32, LL);
        tcvt_kernel<<<gp, tblk, 0, stream>>>(epw,  ePWw, CC, CC, (long)CC*CC, (long)CC*CC, 0, 1);
        tcvt_kernel<<<gp, tblk, 0, stream>>>(dspw, sPWw, CC, CC, (long)CC*CC, (long)CC*CC, 0, 1);
        tcvt_kernel<<<gp, tblk, 0, stream>>>(dcpw, cPWw, CC, CC, (long)CC*CC, (long)CC*CC, 0, 1);
        dim3 g1(FFD / 32, CC / 32, LL);
        tcvt_kernel<<<g1, tblk, 0, stream>>>(ew1, eW1w, CC, FFD, (long)CC*FFD, (long)FFD*CC, 0, 1);
        tcvt_kernel<<<g1, tblk, 0, stream>>>(dw1, dW1w, CC, FFD, (long)CC*FFD, (long)FFD*CC, 0, 1);
        dim3 g2(CC / 32, FFD / 32, LL);
        tcvt_kernel<<<g2, tblk, 0, stream>>>(ew2, eW2w, FFD, CC, (long)FFD*CC, (long)CC*FFD, 0, 1);
        tcvt_kernel<<<g2, tblk, 0, stream>>>(dw2, dW2w, FFD, CC, (long)FFD*CC, (long)CC*FFD, 0, 1);
    }

    // small-mode per-use converters
    auto cvt_qkv = [&](const float* Wq, const float* Wk, const float* Wv) {
        dim3 g(HSZ / 32, CC / 32, HH);
        tcvt_kernel<<<g, tblk, 0, stream>>>(Wq, wb,             CC, HSZ, (long)CC*HSZ, (long)HSZ*CC, 0, 1);
        tcvt_kernel<<<g, tblk, 0, stream>>>(Wk, wb + CC*CC,     CC, HSZ, (long)CC*HSZ, (long)HSZ*CC, 0, 1);
        tcvt_kernel<<<g, tblk, 0, stream>>>(Wv, wb + 2*CC*CC,   CC, HSZ, (long)CC*HSZ, (long)HSZ*CC, 0, 1);
    };
    auto cvt_nt = [&](const float* W, int R, int S) {
        dim3 g(S / 32, R / 32, 1);
        tcvt_kernel<<<g, tblk, 0, stream>>>(W, wb, R, S, 0, 0, 0, 1);
    };

    // ---- encoder ----
    embed_kernel<<<MM, 256, 0, stream>>>(x, wte, wpe_x, enc, encb);
    for (int i = 0; i < LL; ++i) {
        const long cOff = (long)i * CC;
        const __hip_bfloat16 *Wqkv, *Wp, *W1, *W2;
        if (big) {
            Wqkv = eQKVw + (size_t)i * 3072 * CC;
            Wp   = ePWw  + (size_t)i * CC * CC;
            W1   = eW1w  + (size_t)i * FFD * CC;
            W2   = eW2w  + (size_t)i * CC * FFD;
        }
        if (!big) cvt_qkv(eWq + (long)i*HH*CC*HSZ, eWk + (long)i*HH*CC*HSZ, eWv + (long)i*HH*CC*HSZ), Wqkv = wb;
        gemm(encb, Wqkv, nullptr, qkvb, 3072, CC, 3072, false);
        fattn_kernel<false><<<dim3(QT, HH, BB), 256, 0, stream>>>(qkvb, nullptr, a0b);
        if (!big) cvt_nt(epw + (long)i*CC*CC, CC, CC), Wp = wb;
        gemm_sk(a0b, Wp, epb + cOff, t0b, t0c, CC, CC, CC);
        lnb_kernel<<<MM, 256, 0, stream>>>(t0b, t0c, enc, eln1g + cOff, eln1b + cOff, enc, encb);
        if (!big) cvt_nt(ew1 + (long)i*CC*FFD, CC, FFD), W1 = wb;
        gemm(encb, W1, eb1 + (long)i*FFD, ffb, FFD, CC, FFD, true);
        if (!big) cvt_nt(ew2 + (long)i*FFD*CC, FFD, CC), W2 = wb;
        gemm_sk(ffb, W2, eb2 + cOff, t0b, t0c, FFD, CC, CC);
        lnb_kernel<<<MM, 256, 0, stream>>>(t0b, t0c, enc, eln2g + cOff, eln2b + cOff, enc, encb);
    }

    // ---- decoder ----
    embed_kernel<<<MM, 256, 0, stream>>>(y, wte, wpe_y, dec, decb);
    for (int i = 0; i < LL; ++i) {
        const long cOff = (long)i * CC;
        const __hip_bfloat16 *Ws, *Wsp, *Wc, *Wcp, *W1, *W2;
        if (big) {
            Ws  = sQKVw + (size_t)i * 3072 * CC;
            Wsp = sPWw  + (size_t)i * CC * CC;
            Wc  = cQKVw + (size_t)i * 3072 * CC;
            Wcp = cPWw  + (size_t)i * CC * CC;
            W1  = dW1w  + (size_t)i * FFD * CC;
            W2  = dW2w  + (size_t)i * CC * FFD;
        }
        // masked self-attn
        if (!big) cvt_qkv(dsWq + (long)i*HH*CC*HSZ, dsWk + (long)i*HH*CC*HSZ, dsWv + (long)i*HH*CC*HSZ), Ws = wb;
        gemm(decb, Ws, nullptr, qkvb, 3072, CC, 3072, false);
        fattn_kernel<true><<<dim3(QT, HH, BB), 256, 0, stream>>>(qkvb, nullptr, a0b);
        if (!big) cvt_nt(dspw + (long)i*CC*CC, CC, CC), Wsp = wb;
        gemm_sk(a0b, Wsp, dspb + cOff, t0b, t0c, CC, CC, CC);
        lnb_kernel<<<MM, 256, 0, stream>>>(t0b, t0c, dec, dln1g + cOff, dln1b + cOff, dec, decb);
        // cross-attn: q from dec (split-K), k/v from enc
        if (!big) cvt_qkv(dcWq + (long)i*HH*CC*HSZ, dcWk + (long)i*HH*CC*HSZ, dcWv + (long)i*HH*CC*HSZ), Wc = wb;
        gemm_sk(decb, Wc, nullptr, qkvb, qcb, CC, 3072, CC);
        gemm(encb, Wc + (size_t)CC * CC, nullptr, qkvb + CC, 2048, CC, 3072, false);
        fattn_kernel<false><<<dim3(QT, HH, BB), 256, 0, stream>>>(qkvb, qcb, a0b);
        if (!big) cvt_nt(dcpw + (long)i*CC*CC, CC, CC), Wcp = wb;
        gemm_sk(a0b, Wcp, dcpb + cOff, t0b, t0c, CC, CC, CC);
        lnb_kernel<<<MM, 256, 0, stream>>>(t0b, t0c, dec, dln2g + cOff, dln2b + cOff, dec, decb);
        // ffn
        if (!big) cvt_nt(dw1 + (long)i*CC*FFD, CC, FFD), W1 = wb;
        gemm(decb, W1, db1 + (long)i*FFD, ffb, FFD, CC, FFD, true);
        if (!big) cvt_nt(dw2 + (long)i*FFD*CC, FFD, CC), W2 = wb;
        gemm_sk(ffb, W2, db2 + cOff, t0b, t0c, FFD, CC, CC);
        lnb_kernel<<<MM, 256, 0, stream>>>(t0b, t0c, dec, dln3g + cOff, dln3b + cOff, dec, decb);
    }

    // ---- final LN + logits (M-split halves, 128x128 tile — r12 optimum) ----
    ln_kernel<<<MM, 256, 0, stream>>>(dec, nullptr, lnfg, lnfb,
                                      useWteb ? nullptr : t0, t0b);
    if (useWteb) {
        const int GMv = 1024 / 128;                 // 8 m-tiles per half
        const int nwg = GMv * ((VV + 127) / 128);
        mgemm2_kernel<0, false, 128, 128, false><<<nwg, 256, 0, stream>>>(
            t0b, wteb, lm_b, out, nullptr, nullptr, 1024, VV, CC, CC, VV, VV, GMv);
        mgemm2_kernel<0, false, 128, 128, false><<<nwg, 256, 0, stream>>>(
            t0b + (size_t)1024 * CC, wteb, lm_b, out + (size_t)1024 * VV, nullptr, nullptr,
            MM - 1024, VV, CC, CC, VV, VV, GMv);
    } else {
        dim3 grid((VV + 127) / 128, MP / 128);
        mgemm_f32b_kernel<<<grid, 256, 0, stream>>>(t0, wte, lm_b, out, MM, VV, CC, VV);
    }
}